// Round 1
// baseline (3026.740 us; speedup 1.0000x reference)
//
#include <hip/hip_runtime.h>

#define NB   64    // batch
#define NPR  32
#define NPC  32
#define NBD  64
#define NE   128
#define NH   128   // H ; state 2H=256, gates 6H=768, fused K=384, padded N'=1024

// ---- ws layout (float offsets) ----
#define WS_WT    0
#define WS_BIAS  (384*1024)                   // 393216
#define WS_EMB   (WS_BIAS + 1024)             // 394240
#define WS_HNEW  (WS_EMB + 1024*64*128)       // 8782848
#define WS_HCB   (WS_HNEW + 32*64*256)        // 9307136
// total floats = WS_HCB + 2*32*64*128 = 9831424  (~39.3 MB)

// Build fused, gate-interleaved, zero-padded weight Wt[k][o'], k=384, o'=4c+g4.
// A layout: [emb(128) | h_row(128) | h_col(128)].
// g4=0: r-col (W_ih row c    | W_hh row c),   g4=1: z-col (rows 256+c),
// g4=2: xn    (W_ih row 512+c| 0),            g4=3: hn (0 | W_hh row 512+c).
__global__ __launch_bounds__(256) void k_build_wt(
    const float* __restrict__ W_ih, const float* __restrict__ W_hh,
    float* __restrict__ Wt)
{
    int idx = blockIdx.x * 256 + threadIdx.x;   // exactly 384*1024 threads
    int k  = idx >> 10;
    int op = idx & 1023;
    int c = op >> 2, g4 = op & 3;
    float v;
    if (g4 == 0)      v = (k < 128) ? W_ih[c*128 + k]        : W_hh[c*256 + k - 128];
    else if (g4 == 1) v = (k < 128) ? W_ih[(256+c)*128 + k]  : W_hh[(256+c)*256 + k - 128];
    else if (g4 == 2) v = (k < 128) ? W_ih[(512+c)*128 + k]  : 0.0f;
    else              v = (k < 128) ? 0.0f                   : W_hh[(512+c)*256 + k - 128];
    Wt[idx] = v;
}

__global__ __launch_bounds__(256) void k_build_bias(
    const float* __restrict__ b_ih, const float* __restrict__ b_hh,
    float* __restrict__ bias4)
{
    int op = blockIdx.x * 256 + threadIdx.x;    // exactly 1024
    int c = op >> 2, g4 = op & 3;
    float v;
    if (g4 == 0)      v = b_ih[c] + b_hh[c];
    else if (g4 == 1) v = b_ih[256+c] + b_hh[256+c];
    else if (g4 == 2) v = b_ih[512+c];
    else              v = b_hh[512+c];
    bias4[op] = v;
}

// emb[cell][b][e] = x[b][i][j][:] @ We.T + be   (one WG per cell)
__global__ __launch_bounds__(256) void k_emb(
    const float* __restrict__ x, const float* __restrict__ We,
    const float* __restrict__ be, float* __restrict__ emb)
{
    __shared__ __align__(16) float xs[64][72];    // [k][b], pad keeps rows 16B-aligned
    __shared__ __align__(16) float wes[64][128];  // [k][e]
    const int cell = blockIdx.x;
    const int i = cell >> 5, j = cell & 31;
    const int tid = threadIdx.x;
    #pragma unroll
    for (int q = 0; q < 4; ++q) {               // stage x (transpose to [k][b])
        int p = q*256 + tid;
        int b = p >> 4, k4 = p & 15;
        float4 v = *(const float4*)&x[(((b*NPR + i)*NPC + j) << 6) + k4*4];
        xs[k4*4+0][b] = v.x; xs[k4*4+1][b] = v.y;
        xs[k4*4+2][b] = v.z; xs[k4*4+3][b] = v.w;
    }
    #pragma unroll
    for (int q = 0; q < 8; ++q) {               // stage We (transpose to [k][e])
        int p = q*256 + tid;
        int e = p >> 4, k4 = p & 15;
        float4 v = *(const float4*)&We[(e << 6) + k4*4];
        wes[k4*4+0][e] = v.x; wes[k4*4+1][e] = v.y;
        wes[k4*4+2][e] = v.z; wes[k4*4+3][e] = v.w;
    }
    __syncthreads();
    const int bg = tid >> 5, og = tid & 31;     // 8 b-rows x 4 e-cols per thread
    float acc[8][4];
    #pragma unroll
    for (int r = 0; r < 8; ++r) { acc[r][0]=0.f; acc[r][1]=0.f; acc[r][2]=0.f; acc[r][3]=0.f; }
    #pragma unroll 4
    for (int k = 0; k < 64; ++k) {
        float4 a0 = *(const float4*)&xs[k][bg*8];
        float4 a1 = *(const float4*)&xs[k][bg*8+4];
        float4 w  = *(const float4*)&wes[k][og*4];
        float av[8] = {a0.x,a0.y,a0.z,a0.w,a1.x,a1.y,a1.z,a1.w};
        float wv[4] = {w.x,w.y,w.z,w.w};
        #pragma unroll
        for (int r = 0; r < 8; ++r)
            #pragma unroll
            for (int cc = 0; cc < 4; ++cc)
                acc[r][cc] = fmaf(av[r], wv[cc], acc[r][cc]);
    }
    float4 bev = *(const float4*)&be[og*4];
    #pragma unroll
    for (int r = 0; r < 8; ++r) {
        int b = bg*8 + r;
        float4 o;
        o.x = acc[r][0] + bev.x; o.y = acc[r][1] + bev.y;
        o.z = acc[r][2] + bev.z; o.w = acc[r][3] + bev.w;
        *(float4*)&emb[cell*(64*128) + b*128 + og*4] = o;
    }
}

// Per diagonal: fused gate GEMM + gate nonlinearities -> hnew[i][b][c]
// WG = (cell, slice of 16 c-channels = 64 o'-cols). Thread: 4 b-rows x 1 c (4 o').
__global__ __launch_bounds__(256) void k1_gates(
    const float* __restrict__ Wt, const float* __restrict__ bias4,
    const float* __restrict__ emb, const float* __restrict__ hc_prev,
    float* __restrict__ hnew, const int d, const int i0)
{
    __shared__ __align__(16) float As[64][72];   // [k][b]
    __shared__ __align__(16) float Ws[64][64];   // [k][o'_local]
    const int cellIdx = blockIdx.x >> 4;
    const int slice   = blockIdx.x & 15;
    const int i = i0 + cellIdx, j = d - i;
    const int cell = i*NPC + j;
    const int tid = threadIdx.x;
    const int bg = tid >> 4;      // 0..15 -> b rows bg*4..+3
    const int og = tid & 15;      // 0..15 -> c_local
    float4 bv = *(const float4*)&bias4[slice*64 + og*4];
    float acc[4][4];
    #pragma unroll
    for (int r = 0; r < 4; ++r) { acc[r][0]=bv.x; acc[r][1]=bv.y; acc[r][2]=bv.z; acc[r][3]=bv.w; }

    for (int kc = 0; kc < 6; ++kc) {            // K = 6 chunks of 64
        #pragma unroll
        for (int q = 0; q < 4; ++q) {           // stage A chunk, transposed, zero-fill boundaries
            int p = q*256 + tid;
            int b = p >> 4, k4 = p & 15;
            float4 v = make_float4(0.f, 0.f, 0.f, 0.f);
            if (kc < 2) {
                v = *(const float4*)&emb[cell*(64*128) + b*128 + kc*64 + k4*4];
            } else if (kc < 4) {
                if (i > 0) v = *(const float4*)&hc_prev[((i-1)*NB + b)*NH + (kc-2)*64 + k4*4];
            } else {
                if (j > 0) v = *(const float4*)&hc_prev[(i*NB + b)*NH + (kc-4)*64 + k4*4];
            }
            As[k4*4+0][b] = v.x; As[k4*4+1][b] = v.y;
            As[k4*4+2][b] = v.z; As[k4*4+3][b] = v.w;
        }
        #pragma unroll
        for (int q = 0; q < 4; ++q) {           // stage W chunk
            int p = q*256 + tid;
            int kl = p >> 4, c4 = p & 15;
            float4 v = *(const float4*)&Wt[(kc*64 + kl)*1024 + slice*64 + c4*4];
            *(float4*)&Ws[kl][c4*4] = v;
        }
        __syncthreads();
        #pragma unroll 4
        for (int k = 0; k < 64; ++k) {
            float4 a = *(const float4*)&As[k][bg*4];   // broadcast read
            float4 w = *(const float4*)&Ws[k][og*4];
            float av[4] = {a.x,a.y,a.z,a.w};
            float wv[4] = {w.x,w.y,w.z,w.w};
            #pragma unroll
            for (int r = 0; r < 4; ++r)
                #pragma unroll
                for (int cc = 0; cc < 4; ++cc)
                    acc[r][cc] = fmaf(av[r], wv[cc], acc[r][cc]);
        }
        __syncthreads();
    }
    // gates: acc = [xr+hr, xz+hz, xn, hn] (+biases), c = state channel
    const int c = slice*16 + og;
    #pragma unroll
    for (int r = 0; r < 4; ++r) {
        const int b = bg*4 + r;
        float rg = 1.f/(1.f + __expf(-acc[r][0]));
        float zg = 1.f/(1.f + __expf(-acc[r][1]));
        float e2 = __expf(2.f*(acc[r][2] + rg*acc[r][3]));
        float ng = 1.f - 2.f/(e2 + 1.f);                 // tanh
        float hval = 0.f;
        if (c < NH) { if (i > 0) hval = hc_prev[((i-1)*NB + b)*NH + c]; }
        else        { if (j > 0) hval = hc_prev[(i*NB + b)*NH + (c-NH)]; }
        hnew[(i*NB + b)*256 + c] = (1.f - zg)*ng + zg*hval;
    }
}

// Per diagonal: h_c = hnew @ Wc.T + bc ; also emits final output at d==62.
__global__ __launch_bounds__(256) void k2_compress(
    const float* __restrict__ Wc, const float* __restrict__ bc,
    const float* __restrict__ hnew, float* __restrict__ hc_cur,
    float* __restrict__ out, const int d, const int i0)
{
    const int cellIdx = blockIdx.x >> 3;
    const int os = blockIdx.x & 7;      // o-slice of 16
    const int i = i0 + cellIdx;
    const int tid = threadIdx.x;
    const int bg = tid >> 4;            // 4 b-rows
    const int og = tid & 15;
    const int o = os*16 + og;
    const float* hn = hnew + i*(NB*256);
    float acc[4];
    const float bcv = bc[o];
    #pragma unroll
    for (int r = 0; r < 4; ++r) acc[r] = bcv;
    #pragma unroll 4
    for (int k4 = 0; k4 < 64; ++k4) {
        float4 w = *(const float4*)&Wc[o*256 + k4*4];
        #pragma unroll
        for (int r = 0; r < 4; ++r) {
            float4 a = *(const float4*)&hn[(bg*4+r)*256 + k4*4];
            acc[r] += a.x*w.x + a.y*w.y + a.z*w.z + a.w*w.w;
        }
    }
    #pragma unroll
    for (int r = 0; r < 4; ++r) {
        int b = bg*4 + r;
        hc_cur[(i*NB + b)*NH + o] = acc[r];
        if (d == 62) out[b*NH + o] = acc[r];
    }
}

extern "C" void kernel_launch(void* const* d_in, const int* in_sizes, int n_in,
                              void* d_out, int out_size, void* d_ws, size_t ws_size,
                              hipStream_t stream)
{
    const float* x    = (const float*)d_in[0];
    const float* We   = (const float*)d_in[1];
    const float* be   = (const float*)d_in[2];
    const float* W_ih = (const float*)d_in[3];
    const float* b_ih = (const float*)d_in[4];
    const float* W_hh = (const float*)d_in[5];
    const float* b_hh = (const float*)d_in[6];
    const float* Wc   = (const float*)d_in[7];
    const float* bc   = (const float*)d_in[8];
    float* ws    = (float*)d_ws;
    float* Wt    = ws + WS_WT;
    float* bias4 = ws + WS_BIAS;
    float* emb   = ws + WS_EMB;
    float* hnew  = ws + WS_HNEW;
    float* hcb   = ws + WS_HCB;
    float* out   = (float*)d_out;

    k_build_wt<<<1536, 256, 0, stream>>>(W_ih, W_hh, Wt);
    k_build_bias<<<4, 256, 0, stream>>>(b_ih, b_hh, bias4);
    k_emb<<<1024, 256, 0, stream>>>(x, We, be, emb);

    for (int d = 0; d < 63; ++d) {
        int i0 = d > 31 ? d - 31 : 0;
        int i1 = d < 31 ? d : 31;
        int n  = i1 - i0 + 1;
        float* cur  = hcb + (size_t)(d & 1) * (32*NB*NH);
        float* prev = hcb + (size_t)((d & 1) ^ 1) * (32*NB*NH);
        k1_gates<<<n*16, 256, 0, stream>>>(Wt, bias4, emb, prev, hnew, d, i0);
        k2_compress<<<n*8, 256, 0, stream>>>(Wc, bc, hnew, cur, out, d, i0);
    }
}